// Round 1
// baseline (7509.303 us; speedup 1.0000x reference)
//
#include <hip/hip_runtime.h>

typedef unsigned short u16;
typedef __attribute__((ext_vector_type(4))) float f32x4;
typedef __attribute__((ext_vector_type(2))) float f32x2;
typedef __attribute__((ext_vector_type(8))) short short8;

#define B_ 32
#define P_ 196
#define T_ 64
#define E_ 512
#define V_ 32000

__device__ __forceinline__ u16 f2bf(float x){
  unsigned int u = __float_as_uint(x);
  u += 0x7FFFu + ((u >> 16) & 1u);
  return (u16)(u >> 16);
}
__device__ __forceinline__ float sigf(float x){ return 1.0f/(1.0f + __expf(-x)); }
__device__ __forceinline__ float tanhfast(float x){
  float e = __expf(-2.0f*fabsf(x));
  float t = (1.0f - e)/(1.0f + e);
  return x >= 0.0f ? t : -t;
}

// ---------- setup kernels ----------

__global__ __launch_bounds__(256) void k_cvt_bf16(const float* __restrict__ s,
                                                  u16* __restrict__ d, int n8){
  int i = blockIdx.x*256 + threadIdx.x;
  if (i >= n8) return;
  const f32x4* sp = (const f32x4*)(s + (size_t)i*8);
  f32x4 a = sp[0], b = sp[1];
  short8 v;
#pragma unroll
  for (int j=0;j<4;++j){ v[j] = (short)f2bf(a[j]); v[4+j] = (short)f2bf(b[j]); }
  *(short8*)(d + (size_t)i*8) = v;
}

// W_enc [512][512] (k-major rows) -> WT [a][k] bf16
__global__ __launch_bounds__(256) void k_wencT(const float* __restrict__ W, u16* __restrict__ WT){
  int tid = threadIdx.x;
  int kc = tid & 63, a = blockIdx.x*4 + (tid >> 6);
  short8 v;
#pragma unroll
  for (int j=0;j<8;++j) v[j] = (short)f2bf(W[(kc*8+j)*512 + a]);
  *(short8*)(WT + a*512 + kc*8) = v;
}

__global__ __launch_bounds__(256) void k_mean(const float* __restrict__ enc, float* __restrict__ mean){
  int b = blockIdx.x, tid = threadIdx.x;
  f32x2 acc; acc.x = 0.f; acc.y = 0.f;
  for (int p=0;p<P_;++p){
    f32x2 v = *(const f32x2*)(enc + ((size_t)(b*P_+p))*512 + tid*2);
    acc.x += v.x; acc.y += v.y;
  }
  acc.x *= (1.0f/196.0f); acc.y *= (1.0f/196.0f);
  *(f32x2*)(mean + b*512 + tid*2) = acc;
}

// h/c init: Mh = mean @ W_init_h + b  [32][1024], reshaped (2,32,512) flat
__global__ __launch_bounds__(256) void k_init_state(const float* __restrict__ mean,
    const float* __restrict__ Wh, const float* __restrict__ bh,
    const float* __restrict__ Wc, const float* __restrict__ bc,
    float* __restrict__ h0, float* __restrict__ h1,
    float* __restrict__ c0, float* __restrict__ c1){
  int bid = blockIdx.x;
  int which = bid >> 7, r = (bid >> 2) & 31, jg = bid & 3;
  const float* W = which ? Wc : Wh;
  const float* bb = which ? bc : bh;
  __shared__ float m[512];
  for (int i=threadIdx.x; i<512; i+=256) m[i] = mean[r*512 + i];
  __syncthreads();
  int j = jg*256 + threadIdx.x;
  float acc = bb[j];
  for (int e=0;e<512;++e) acc += m[e]*W[e*1024 + j];
  int l = r >> 4;
  int bb2 = ((r & 15) << 1) | (j >> 9);
  int hh = j & 511;
  float* dst = which ? (l ? c1 : c0) : (l ? h1 : h0);
  dst[bb2*512 + hh] = acc;
}

// ---------- generic bf16 GEMM: C[M][N] = A[M][512] * Bm[N][512]^T + bias ----------
// grid (M/128, N/128), 256 threads, 4 waves each owning a 64x64 quadrant.
__global__ __launch_bounds__(256) void k_gemm_bf16(
    const u16* __restrict__ A, const u16* __restrict__ Bm,
    const float* __restrict__ bias, float* __restrict__ C, int N){
  __shared__ __align__(16) u16 As[128*32];
  __shared__ __align__(16) u16 Bs[128*32];
  int tid = threadIdx.x, l = tid & 63, w = tid >> 6;
  int m0 = blockIdx.x * 128, n0 = blockIdx.y * 128;
  int wm = w >> 1, wn = w & 1;
  f32x4 acc[4][4];
#pragma unroll
  for (int a=0;a<4;++a)
#pragma unroll
    for (int b=0;b<4;++b) acc[a][b] = (f32x4)0.0f;

  int srow = tid >> 2, schunk = tid & 3;
  const u16* gA = A + (size_t)(m0 + srow)*512 + schunk*8;
  const u16* gB = Bm + (size_t)(n0 + srow)*512 + schunk*8;
  int lr = l & 15, lk = (l >> 4) * 8;

  for (int k0 = 0; k0 < 512; k0 += 32){
    short8 va0 = *(const short8*)(gA + k0);
    short8 va1 = *(const short8*)(gA + (size_t)64*512 + k0);
    short8 vb0 = *(const short8*)(gB + k0);
    short8 vb1 = *(const short8*)(gB + (size_t)64*512 + k0);
    __syncthreads();
    *(short8*)(As + srow*32 + schunk*8) = va0;
    *(short8*)(As + (64+srow)*32 + schunk*8) = va1;
    *(short8*)(Bs + srow*32 + schunk*8) = vb0;
    *(short8*)(Bs + (64+srow)*32 + schunk*8) = vb1;
    __syncthreads();
    short8 af[4], bfv[4];
#pragma unroll
    for (int mt=0; mt<4; ++mt) af[mt]  = *(const short8*)(As + (wm*64 + mt*16 + lr)*32 + lk);
#pragma unroll
    for (int nt=0; nt<4; ++nt) bfv[nt] = *(const short8*)(Bs + (wn*64 + nt*16 + lr)*32 + lk);
#pragma unroll
    for (int mt=0; mt<4; ++mt)
#pragma unroll
      for (int nt=0; nt<4; ++nt)
        acc[mt][nt] = __builtin_amdgcn_mfma_f32_16x16x32_bf16(af[mt], bfv[nt], acc[mt][nt], 0, 0, 0);
  }
#pragma unroll
  for (int mt=0; mt<4; ++mt){
    int row = m0 + wm*64 + mt*16 + ((l >> 4) << 2);
#pragma unroll
    for (int nt=0; nt<4; ++nt){
      int col = n0 + wn*64 + nt*16 + (l & 15);
      float bv = bias[col];
#pragma unroll
      for (int j=0;j<4;++j)
        C[(size_t)(row + j)*N + col] = acc[mt][nt][j] + bv;
    }
  }
}

// ---------- per-step kernels ----------

// attention: att2 (redundant per p-group), e, exp, partial sum + partial context
// grid 256 = (b<<3)|pg, 256 threads
__global__ __launch_bounds__(256) void k_attn(
    const float* __restrict__ h1_in, const float* __restrict__ Wdec,
    const float* __restrict__ bdec, const float* __restrict__ encatt,
    const float* __restrict__ Wfull, const float* __restrict__ bfull,
    const float* __restrict__ enc,
    float* __restrict__ Spart, float* __restrict__ ctxpart){
  int b = blockIdx.x >> 3, pg = blockIdx.x & 7;
  int p0 = pg*25, pcnt = min(25, P_ - p0);
  int tid = threadIdx.x, l = tid & 63, w = tid >> 6;
  __shared__ float h1s[512];
  __shared__ float att2s[2][512];
  __shared__ float wsm[32];
  for (int i=tid; i<512; i+=256) h1s[i] = h1_in[b*512 + i];
  __syncthreads();
  // att2: threads (a4 = (tid&127)*4, kh = tid>>7)
  {
    int a0 = (tid & 127)*4, kh = tid >> 7;
    f32x4 acc;
    if (kh == 0) acc = *(const f32x4*)(bdec + a0); else acc = (f32x4)0.0f;
    int h0i = kh*256;
    for (int h=h0i; h<h0i+256; ++h){
      f32x4 wv = *(const f32x4*)(Wdec + (size_t)h*512 + a0);
      float hv = h1s[h];
      acc.x += hv*wv.x; acc.y += hv*wv.y; acc.z += hv*wv.z; acc.w += hv*wv.w;
    }
    *(f32x4*)(&att2s[kh][a0]) = acc;
  }
  __syncthreads();
  // per-lane regs for this lane's 8 a's
  float a2r[8], wfr[8];
  {
    f32x4 s0 = *(const f32x4*)(&att2s[0][l*8]), s1 = *(const f32x4*)(&att2s[0][l*8+4]);
    f32x4 t0 = *(const f32x4*)(&att2s[1][l*8]), t1 = *(const f32x4*)(&att2s[1][l*8+4]);
#pragma unroll
    for (int j=0;j<4;++j){ a2r[j] = s0[j]+t0[j]; a2r[4+j] = s1[j]+t1[j]; }
    f32x4 w0 = *(const f32x4*)(Wfull + l*8), w1 = *(const f32x4*)(Wfull + l*8 + 4);
#pragma unroll
    for (int j=0;j<4;++j){ wfr[j] = w0[j]; wfr[4+j] = w1[j]; }
  }
  float bf0 = bfull[0];
  // e + exp, wave per p
  for (int i = 0; w + i*4 < pcnt; ++i){
    int pl = w + i*4;
    const float* ep = encatt + ((size_t)(b*P_ + p0 + pl))*512 + l*8;
    f32x4 e0 = *(const f32x4*)(ep);
    f32x4 e1 = *(const f32x4*)(ep + 4);
    float s = 0.f;
#pragma unroll
    for (int j=0;j<4;++j){
      s += fmaxf(e0[j] + a2r[j],   0.f) * wfr[j];
      s += fmaxf(e1[j] + a2r[4+j], 0.f) * wfr[4+j];
    }
#pragma unroll
    for (int o=32;o>=1;o>>=1) s += __shfl_xor(s, o);
    if (l == 0) wsm[pl] = __expf(s + bf0);
  }
  __syncthreads();
  if (tid < 64){
    float sv = (tid < pcnt) ? wsm[tid] : 0.f;
#pragma unroll
    for (int o=32;o>=1;o>>=1) sv += __shfl_xor(sv, o);
    if (tid == 0) Spart[b*8 + pg] = sv;
  }
  // partial context: thread owns a-pair
  {
    f32x2 cacc; cacc.x = 0.f; cacc.y = 0.f;
    for (int q=0; q<pcnt; ++q){
      float wq = wsm[q];
      f32x2 ev = *(const f32x2*)(enc + ((size_t)(b*P_ + p0 + q))*512 + tid*2);
      cacc.x += wq*ev.x; cacc.y += wq*ev.y;
    }
    *(f32x2*)(ctxpart + (size_t)(b*8 + pg)*512 + tid*2) = cacc;
  }
}

// LSTM layer 0. grid 256 = (b<<3)|mg, 256 threads (4 waves x 16 cells)
__global__ __launch_bounds__(256) void k_lstm0(
    const int* __restrict__ caps, int t, const float* __restrict__ embW,
    const float* __restrict__ Spart, const float* __restrict__ ctxpart,
    const float* __restrict__ h0_in, const float* __restrict__ c0_in,
    const float* __restrict__ Wih0, const float* __restrict__ Whh0,
    const float* __restrict__ bih0, const float* __restrict__ bhh0,
    float* __restrict__ h0_out, float* __restrict__ c0_out){
  int b = blockIdx.x >> 3, mg = blockIdx.x & 7;
  int tid = threadIdx.x, l = tid & 63, w = tid >> 6;
  __shared__ float rinv_s;
  if (tid == 0){
    float S = 0.f;
#pragma unroll
    for (int g=0; g<8; ++g) S += Spart[b*8 + g];
    rinv_s = 1.0f/S;
  }
  __syncthreads();
  float rinv = rinv_s;
  int cap = caps[b*T_ + t];
  float xe[8], xc[8], xh[8];
  {
    const float* ep = embW + (size_t)cap*512 + l*8;
    f32x4 a0 = *(const f32x4*)(ep), a1 = *(const f32x4*)(ep+4);
#pragma unroll
    for (int j=0;j<4;++j){ xe[j]=a0[j]; xe[4+j]=a1[j]; }
    f32x4 c0v = (f32x4)0.0f, c1v = (f32x4)0.0f;
#pragma unroll
    for (int g=0; g<8; ++g){
      const float* cp = ctxpart + (size_t)(b*8+g)*512 + l*8;
      f32x4 p0 = *(const f32x4*)(cp), p1 = *(const f32x4*)(cp+4);
      c0v.x+=p0.x; c0v.y+=p0.y; c0v.z+=p0.z; c0v.w+=p0.w;
      c1v.x+=p1.x; c1v.y+=p1.y; c1v.z+=p1.z; c1v.w+=p1.w;
    }
#pragma unroll
    for (int j=0;j<4;++j){ xc[j]=c0v[j]*rinv; xc[4+j]=c1v[j]*rinv; }
    const float* hp = h0_in + b*512 + l*8;
    f32x4 h0v = *(const f32x4*)(hp), h1v = *(const f32x4*)(hp+4);
#pragma unroll
    for (int j=0;j<4;++j){ xh[j]=h0v[j]; xh[4+j]=h1v[j]; }
  }
  for (int ci=0; ci<16; ++ci){
    int mc = mg*64 + w*16 + ci;
    float g4[4];
#pragma unroll
    for (int gi=0; gi<4; ++gi){
      int r = gi*512 + mc;
      const float* wi = Wih0 + (size_t)r*1024 + l*8;
      const float* wh = Whh0 + (size_t)r*512 + l*8;
      f32x4 wa0 = *(const f32x4*)(wi),      wa1 = *(const f32x4*)(wi+4);
      f32x4 wb0 = *(const f32x4*)(wi+512),  wb1 = *(const f32x4*)(wi+516);
      f32x4 wc0 = *(const f32x4*)(wh),      wc1 = *(const f32x4*)(wh+4);
      float s = 0.f;
#pragma unroll
      for (int j=0;j<4;++j){
        s += xe[j]*wa0[j] + xe[4+j]*wa1[j];
        s += xc[j]*wb0[j] + xc[4+j]*wb1[j];
        s += xh[j]*wc0[j] + xh[4+j]*wc1[j];
      }
      g4[gi] = s;
    }
#pragma unroll
    for (int o=32;o>=1;o>>=1){
      g4[0] += __shfl_xor(g4[0], o);
      g4[1] += __shfl_xor(g4[1], o);
      g4[2] += __shfl_xor(g4[2], o);
      g4[3] += __shfl_xor(g4[3], o);
    }
    if (l == 0){
      float gi_ = g4[0] + bih0[mc]        + bhh0[mc];
      float gf_ = g4[1] + bih0[512+mc]    + bhh0[512+mc];
      float gg_ = g4[2] + bih0[1024+mc]   + bhh0[1024+mc];
      float go_ = g4[3] + bih0[1536+mc]   + bhh0[1536+mc];
      float cp = c0_in[b*512 + mc];
      float cn = sigf(gf_)*cp + sigf(gi_)*tanhfast(gg_);
      float hn = sigf(go_)*tanhfast(cn);
      c0_out[b*512 + mc] = cn;
      h0_out[b*512 + mc] = hn;
    }
  }
}

// LSTM layer 1 + h1_all store. grid 256 = (b<<3)|mg
__global__ __launch_bounds__(256) void k_lstm1(
    const float* __restrict__ h0_cur, const float* __restrict__ h1_in,
    const float* __restrict__ c1_in,
    const float* __restrict__ Wih1, const float* __restrict__ Whh1,
    const float* __restrict__ bih1, const float* __restrict__ bhh1,
    float* __restrict__ h1_out, float* __restrict__ c1_out,
    u16* __restrict__ h1_all, int t){
  int b = blockIdx.x >> 3, mg = blockIdx.x & 7;
  int tid = threadIdx.x, l = tid & 63, w = tid >> 6;
  float xa[8], xb[8];
  {
    const float* ap = h0_cur + b*512 + l*8;
    f32x4 a0 = *(const f32x4*)(ap), a1 = *(const f32x4*)(ap+4);
    const float* bp = h1_in + b*512 + l*8;
    f32x4 b0 = *(const f32x4*)(bp), b1 = *(const f32x4*)(bp+4);
#pragma unroll
    for (int j=0;j<4;++j){ xa[j]=a0[j]; xa[4+j]=a1[j]; xb[j]=b0[j]; xb[4+j]=b1[j]; }
  }
  for (int ci=0; ci<16; ++ci){
    int mc = mg*64 + w*16 + ci;
    float g4[4];
#pragma unroll
    for (int gi=0; gi<4; ++gi){
      int r = gi*512 + mc;
      const float* wi = Wih1 + (size_t)r*512 + l*8;
      const float* wh = Whh1 + (size_t)r*512 + l*8;
      f32x4 wa0 = *(const f32x4*)(wi), wa1 = *(const f32x4*)(wi+4);
      f32x4 wb0 = *(const f32x4*)(wh), wb1 = *(const f32x4*)(wh+4);
      float s = 0.f;
#pragma unroll
      for (int j=0;j<4;++j){
        s += xa[j]*wa0[j] + xa[4+j]*wa1[j];
        s += xb[j]*wb0[j] + xb[4+j]*wb1[j];
      }
      g4[gi] = s;
    }
#pragma unroll
    for (int o=32;o>=1;o>>=1){
      g4[0] += __shfl_xor(g4[0], o);
      g4[1] += __shfl_xor(g4[1], o);
      g4[2] += __shfl_xor(g4[2], o);
      g4[3] += __shfl_xor(g4[3], o);
    }
    if (l == 0){
      float gi_ = g4[0] + bih1[mc]      + bhh1[mc];
      float gf_ = g4[1] + bih1[512+mc]  + bhh1[512+mc];
      float gg_ = g4[2] + bih1[1024+mc] + bhh1[1024+mc];
      float go_ = g4[3] + bih1[1536+mc] + bhh1[1536+mc];
      float cp = c1_in[b*512 + mc];
      float cn = sigf(gf_)*cp + sigf(gi_)*tanhfast(gg_);
      float hn = sigf(go_)*tanhfast(cn);
      c1_out[b*512 + mc] = cn;
      h1_out[b*512 + mc] = hn;
      h1_all[((size_t)(b*T_ + t))*512 + mc] = f2bf(hn);
    }
  }
}

// ---------- host ----------

extern "C" void kernel_launch(void* const* d_in, const int* in_sizes, int n_in,
                              void* d_out, int out_size, void* d_ws, size_t ws_size,
                              hipStream_t stream){
  const float* enc   = (const float*)d_in[0];
  const int*   caps  = (const int*)d_in[1];
  const float* embW  = (const float*)d_in[2];
  const float* fc_b  = (const float*)d_in[3];
  const float* Wenc  = (const float*)d_in[4];
  const float* benc  = (const float*)d_in[5];
  const float* Wdec  = (const float*)d_in[6];
  const float* bdec  = (const float*)d_in[7];
  const float* Wfull = (const float*)d_in[8];
  const float* bfull = (const float*)d_in[9];
  const float* Wih0  = (const float*)d_in[10];
  const float* Whh0  = (const float*)d_in[11];
  const float* bih0  = (const float*)d_in[12];
  const float* bhh0  = (const float*)d_in[13];
  const float* Wih1  = (const float*)d_in[14];
  const float* Whh1  = (const float*)d_in[15];
  const float* bih1  = (const float*)d_in[16];
  const float* bhh1  = (const float*)d_in[17];
  const float* Winh  = (const float*)d_in[18];
  const float* binh  = (const float*)d_in[19];
  const float* Winc  = (const float*)d_in[20];
  const float* binc  = (const float*)d_in[21];
  float* out = (float*)d_out;

  char* wsp = (char*)d_ws;
  size_t off = 0;
  auto alloc = [&](size_t bytes)->char*{
    char* p = wsp + off;
    off += (bytes + 255) & ~(size_t)255;
    return p;
  };
  u16*   A_enc   = (u16*)  alloc((size_t)6272*512*2);
  u16*   emb_bf  = (u16*)  alloc((size_t)V_*512*2);
  u16*   WencT   = (u16*)  alloc((size_t)512*512*2);
  float* encatt  = (float*)alloc((size_t)6272*512*4);
  float* meanb   = (float*)alloc((size_t)32*512*4);
  float* h0s[2]  = {(float*)alloc(32*512*4), (float*)alloc(32*512*4)};
  float* h1s[2]  = {(float*)alloc(32*512*4), (float*)alloc(32*512*4)};
  float* c0s[2]  = {(float*)alloc(32*512*4), (float*)alloc(32*512*4)};
  float* c1s[2]  = {(float*)alloc(32*512*4), (float*)alloc(32*512*4)};
  float* Spart   = (float*)alloc(32*8*4);
  float* ctxpart = (float*)alloc((size_t)32*8*512*4);
  u16*   h1_all  = (u16*)  alloc((size_t)2048*512*2);
  if (off > ws_size) return;  // workspace too small; bail (will fail validation visibly)

  // setup
  k_cvt_bf16<<<1568, 256, 0, stream>>>(enc, A_enc, 401408);
  k_cvt_bf16<<<8000, 256, 0, stream>>>(embW, emb_bf, 2048000);
  k_wencT   <<<128, 256, 0, stream>>>(Wenc, WencT);
  k_mean    <<<32, 256, 0, stream>>>(enc, meanb);
  k_init_state<<<256, 256, 0, stream>>>(meanb, Winh, binh, Winc, binc,
                                        h0s[0], h1s[0], c0s[0], c1s[0]);
  // enc_att = encoder_out @ W_enc + b_enc  (6272x512x512)
  k_gemm_bf16<<<dim3(49, 4), 256, 0, stream>>>(A_enc, WencT, benc, encatt, 512);

  // recurrence
  for (int t=0; t<T_; ++t){
    int pi = t & 1, po = pi ^ 1;
    k_attn <<<256, 256, 0, stream>>>(h1s[pi], Wdec, bdec, encatt, Wfull, bfull,
                                     enc, Spart, ctxpart);
    k_lstm0<<<256, 256, 0, stream>>>(caps, t, embW, Spart, ctxpart,
                                     h0s[pi], c0s[pi], Wih0, Whh0, bih0, bhh0,
                                     h0s[po], c0s[po]);
    k_lstm1<<<256, 256, 0, stream>>>(h0s[po], h1s[pi], c1s[pi],
                                     Wih1, Whh1, bih1, bhh1,
                                     h1s[po], c1s[po], h1_all, t);
  }

  // deferred tied-weight projection: out[2048][32000] = h1_all @ emb_W^T + fc_b
  k_gemm_bf16<<<dim3(16, 250), 256, 0, stream>>>(h1_all, emb_bf, fc_b, out, V_);
}